// Round 6
// baseline (285.498 us; speedup 1.0000x reference)
//
#include <hip/hip_runtime.h>
#include <hip/hip_bf16.h>
#include <stdint.h>

// Problem constants (B=8192, D=256 fixed by reference setup_inputs)
#define NB 8192          // batch rows
#define ND 256           // feature dim (= full K)
#define NW 16384         // rows of W = [v; u]
#define BM 128           // rows per block
#define BN 64            // cols per panel
#define NSTRIP 4         // column strips
#define STRIPW 4096      // cols per strip
#define NPANEL (STRIPW / BN)   // 64 panels per block
// rows pre-scaled by rw*sqrt(1/T): every dot product == sim/T directly
#define SQRT_INVT 3.7796447f   // sqrt(1/0.07)

typedef __bf16 bf16x8 __attribute__((ext_vector_type(8)));
typedef float floatx4 __attribute__((ext_vector_type(4)));

__device__ __forceinline__ void gload_lds16(const void* g, void* l) {
    // async global->LDS, 16B per lane; LDS dest = wave-uniform base + lane*16
    __builtin_amdgcn_global_load_lds(
        (const __attribute__((address_space(1))) unsigned int*)g,
        (__attribute__((address_space(3))) unsigned int*)l,
        16, 0, 0);
}

// ---------------------------------------------------------------------------
// Kernel 1: W[row] = concat(v,u)[row] * (1/||row||) * sqrt(1/T), in bf16.
// One WAVE per row. Also zeroes out[0] for finalize's atomicAdd.
// ---------------------------------------------------------------------------
__global__ __launch_bounds__(512) void prep_kernel(
    const float* __restrict__ u, const float* __restrict__ v,
    __hip_bfloat16* __restrict__ W, float* __restrict__ out)
{
    const int t    = threadIdx.x;
    if (blockIdx.x == 0 && t == 0) out[0] = 0.f;
    const int row  = blockIdx.x * 8 + (t >> 6);       // 0..16383
    const int lane = t & 63;
    const float* src = (row < NB) ? (v + (size_t)row * ND)
                                  : (u + (size_t)(row - NB) * ND);
    float4 x = ((const float4*)src)[lane];
    float ss = x.x * x.x + x.y * x.y + x.z * x.z + x.w * x.w;
#pragma unroll
    for (int off = 1; off < 64; off <<= 1) ss += __shfl_xor(ss, off, 64);
    const float sc = rsqrtf(ss) * SQRT_INVT;          // norms ~16, eps clamp moot
    ushort4 o;
    __hip_bfloat16 h;
    h = __float2bfloat16(x.x * sc); o.x = *(const unsigned short*)&h;
    h = __float2bfloat16(x.y * sc); o.y = *(const unsigned short*)&h;
    h = __float2bfloat16(x.z * sc); o.z = *(const unsigned short*)&h;
    h = __float2bfloat16(x.w * sc); o.w = *(const unsigned short*)&h;
    ((ushort4*)(W + (size_t)row * ND))[lane] = o;
}

// ---------------------------------------------------------------------------
// Kernel 2: fused GEMM+exp+rowsum -- m201-style counted-vmcnt panel pipeline.
// Round-5 post-mortem: all drain-style schedules converge to 36-40% MfmaUtil;
// serial regions (MFMA 33us + VALU/exp 27us + L2 staging) simply add up.
// This round ports the verified T3+T4+T5 stack (m218: counted vmcnt across
// RAW s_barrier = +38-73%) at the same occupancy (512 thr, 128KB LDS,
// 1 block/CU -- occupancy is NOT the wall, m201 hits 62% here):
//  - B panels (64 cols x 256 K = 32 KB) staged BLOCK-SHARED (halves L2
//    traffic vs r2/r5's private staging: 0.5 GB total) into ring-4 slots.
//  - Per panel: vmcnt(8) [2 panels stay in flight, slack = 2 iterations]
//    -> raw s_barrier (NO compiler vmcnt(0) drain) -> stage panel t+3
//    (recycles slot t-1: everyone finished reading it >=3 barriers ago)
//    -> 32 MFMA with the PREVIOUS panel's 16 exps unfenced behind them
//    (ping-pong accA/accB, static parity -- rule 20) so exp fills MFMA
//    shadows. setprio(1) around the MFMA+epi cluster (T5; pays with
//    phase-split, m218b).
//  - pos diagonal captured in a register (posv), stored after the loop:
//    no vmem stores in the loop -> vmcnt counts stay exact.
//  - A fragments global->reg (af[4][8], 32 VGPR), one-time from L2.
// LDS swizzle (verified r1/r4): 16B chunk c of row r at c^(r&15); linear
// dest + inverse-swizzled source + swizzle on read (rule 21).
// XCD map: s=(b>>1)&3, rt=((b>>3)<<1)|(b&1).
// ---------------------------------------------------------------------------
__global__ __launch_bounds__(512, 2) void dcl_main(
    const __hip_bfloat16* __restrict__ W,   // 16384 x 256, pre-scaled
    float* __restrict__ partial,            // [4][8192] slot = strip
    float* __restrict__ pos)                // 8192
{
    const int b  = blockIdx.x;
    const int s  = (b >> 1) & 3;                    // strip; XCD(b)=b%8 in {2s,2s+1}
    const int rt = ((b >> 3) << 1) | (b & 1);       // row tile 0..63
    const int rb = rt * BM;

    const __hip_bfloat16* A = W + (size_t)NB * ND;  // u rows

    __shared__ __align__(16) char lds[131072];      // ring-4 x 32 KB panels

    const int tid  = threadIdx.x;
    const int wave = tid >> 6;
    const int lane = tid & 63;
    const int wm   = wave >> 2;             // 0..1 : 64-row group of A
    const int wn   = wave & 3;              // 0..3 : 16-col group of panel
    const int quad = lane >> 4;             // 0..3
    const int tcol = lane & 15;             // 0..15

    const int sbase = s * STRIPW;

#define WAITV(N) asm volatile("s_waitcnt vmcnt(" #N ")" ::: "memory")

#define STAGE(T, SLOT) do {                                                  \
    const int cbS_ = sbase + (T) * BN;                                       \
    char* dstS_ = lds + (SLOT) * 32768;                                      \
    _Pragma("unroll")                                                        \
    for (int i_ = 0; i_ < 4; i_++) {                                         \
        int o_ = i_ * 8192 + wave * 1024 + lane * 16;                        \
        int r_ = o_ >> 9;                        /* 512 B per row */         \
        int c_ = (o_ >> 4) & 31;                 /* 16B chunk */             \
        int cg_ = (c_ ^ (r_ & 15)) * 8;          /* swizzled k-offset */     \
        gload_lds16(W + (size_t)(cbS_ + r_) * ND + cg_,                      \
                    dstS_ + i_ * 8192 + wave * 1024);                        \
    }                                                                        \
} while (0)

#define COMPUTE(SLOT, ACC) do {                                              \
    const char* sbC_ = lds + (SLOT) * 32768;                                 \
    _Pragma("unroll")                                                        \
    for (int mt_ = 0; mt_ < 4; mt_++) ACC[mt_] = (floatx4){0.f,0.f,0.f,0.f}; \
    _Pragma("unroll")                                                        \
    for (int ks_ = 0; ks_ < 8; ks_++) {                                      \
        bf16x8 bb_ = *(const bf16x8*)(sbC_ + (wn * 16 + tcol) * 512 +        \
                                      ((((ks_ * 4) + quad) ^ tcol) << 4));   \
        _Pragma("unroll")                                                    \
        for (int mt_ = 0; mt_ < 4; mt_++)                                    \
            ACC[mt_] = __builtin_amdgcn_mfma_f32_16x16x32_bf16(              \
                af[mt_][ks_], bb_, ACC[mt_], 0, 0, 0);                       \
    }                                                                        \
} while (0)

// Epilogue of panel TP (acc ACCP). C/D layout: col=lane&15, row=quad*4+reg.
// Diag panel: capture pos into posv (reg), subtract its exp from rsum.
#define EPIFIX(ACCP, TP) do {                                                \
    const int cbP_ = sbase + (TP) * BN;                                      \
    if (cbP_ != dp) {                                                        \
        _Pragma("unroll")                                                    \
        for (int mt_ = 0; mt_ < 4; mt_++)                                    \
            _Pragma("unroll")                                                \
            for (int rg_ = 0; rg_ < 4; rg_++)                                \
                rsum[mt_][rg_] += __expf(ACCP[mt_][rg_]);                    \
    } else {                                                                 \
        _Pragma("unroll")                                                    \
        for (int mt_ = 0; mt_ < 4; mt_++)                                    \
            _Pragma("unroll")                                                \
            for (int rg_ = 0; rg_ < 4; rg_++) {                              \
                int rl_ = mt_ * 16 + quad * 4 + rg_;                         \
                bool sel_ = (rl_ == wn * 16 + tcol);                         \
                float sc_ = ACCP[mt_][rg_];                                  \
                if (sel_) posv = sc_;                                        \
                rsum[mt_][rg_] += sel_ ? 0.f : __expf(sc_);                  \
            }                                                                \
    }                                                                        \
} while (0)

// One panel: counted wait -> raw barrier -> prefetch t+3 -> MFMA + prev epi.
#define PANEL(T, SLOT, ACCC, ACCP, NW, DOSTAGE) do {                         \
    WAITV(NW);                                                               \
    __builtin_amdgcn_s_barrier();                                            \
    if (DOSTAGE) STAGE((T) + 3, ((SLOT) + 3) & 3);                           \
    __builtin_amdgcn_s_setprio(1);                                           \
    COMPUTE(SLOT, ACCC);                                                     \
    EPIFIX(ACCP, (T) - 1);                                                   \
    __builtin_amdgcn_s_setprio(0);                                           \
} while (0)

    // ---- A fragments: global -> registers (32 VGPRs), issued FIRST so the
    // compiler's af-guard vmcnt never drains staged panels ----
    bf16x8 af[4][8];
#pragma unroll
    for (int mt = 0; mt < 4; mt++) {
        const __hip_bfloat16* ar =
            A + (size_t)(rb + wm * 64 + mt * 16 + tcol) * ND + quad * 8;
#pragma unroll
        for (int ks = 0; ks < 8; ks++)
            af[mt][ks] = *(const bf16x8*)(ar + ks * 32);
    }

    // prologue: panels 0..2 in flight
    STAGE(0, 0); STAGE(1, 1); STAGE(2, 2);

    // diag panel (wave-uniform): dp = global col base of this wave's diag blk
    const bool isuv = (s < 2);
    int dp = rb + wm * 64 + (isuv ? 0 : NB);
    const bool dvalid = ((dp >> 12) == s);
    if (!dvalid) dp = 0x40000000;           // sentinel: never matches

    float rsum[4][4];
#pragma unroll
    for (int mt = 0; mt < 4; mt++)
#pragma unroll
        for (int rg = 0; rg < 4; rg++) rsum[mt][rg] = 0.f;

    float posv = 0.f;
    floatx4 accA[4], accB[4];
#pragma unroll
    for (int mt = 0; mt < 4; mt++)
        accB[mt] = (floatx4){-1e38f, -1e38f, -1e38f, -1e38f};  // exp -> 0

#pragma unroll 1
    for (int t = 0; t < NPANEL - 4; t += 4) {
        PANEL(t + 0, 0, accA, accB, 8, 1);
        PANEL(t + 1, 1, accB, accA, 8, 1);
        PANEL(t + 2, 2, accA, accB, 8, 1);
        PANEL(t + 3, 3, accB, accA, 8, 1);
    }
    PANEL(60, 0, accA, accB, 8, 1);   // stages panel 63 -> slot 3
    PANEL(61, 1, accB, accA, 8, 0);
    PANEL(62, 2, accA, accB, 4, 0);
    PANEL(63, 3, accB, accA, 0, 0);
    EPIFIX(accB, 63);                 // last panel's epilogue

#undef WAITV
#undef STAGE
#undef COMPUTE
#undef EPIFIX
#undef PANEL

    // diagonal pos store (uv only): lane (quad,tcol) with quad==tcol>>2
    // captured row rb+wm*64+wn*16+tcol
    if (isuv && dvalid && (tcol >> 2) == quad)
        pos[rb + wm * 64 + wn * 16 + tcol] = posv;

    __syncthreads();   // all panel reads done before LDS reuse

    // block-end reduction: quad-lane shuffle, then combine the 4 wn waves in LDS
#pragma unroll
    for (int mt = 0; mt < 4; mt++)
#pragma unroll
        for (int reg = 0; reg < 4; reg++) {
            float vsum = rsum[mt][reg];
            vsum += __shfl_xor(vsum, 1, 64);
            vsum += __shfl_xor(vsum, 2, 64);
            vsum += __shfl_xor(vsum, 4, 64);
            vsum += __shfl_xor(vsum, 8, 64);
            if (tcol == 0) {
                int lrow = wm * 64 + mt * 16 + quad * 4 + reg;
                ((float*)lds)[wn * 128 + lrow] = vsum;
            }
        }
    __syncthreads();
    if (tid < BM) {
        const float* lf = (const float*)lds;
        float t = lf[tid] + lf[128 + tid] + lf[256 + tid] + lf[384 + tid];
        partial[(size_t)s * NB + rb + tid] = t;
    }
}

// ---------------------------------------------------------------------------
// Kernel 3: loss = mean_i( log(sum_strips partial[s][i]) - pos_i )
// 32 blocks x 256 thr, device atomicAdd into out[0] (zeroed by prep).
// ---------------------------------------------------------------------------
__global__ __launch_bounds__(256) void finalize_kernel(
    const float* __restrict__ partial, const float* __restrict__ pos,
    float* __restrict__ out)
{
    const int i = blockIdx.x * 256 + threadIdx.x;   // 0..8191
    float tot = partial[i] + partial[NB + i] + partial[2 * NB + i]
              + partial[3 * NB + i];
    float sv = logf(tot) - pos[i];
#pragma unroll
    for (int off = 32; off > 0; off >>= 1) sv += __shfl_down(sv, off, 64);
    __shared__ float wsum[4];
    const int t = threadIdx.x;
    if ((t & 63) == 0) wsum[t >> 6] = sv;
    __syncthreads();
    if (t == 0) {
        float blk = (wsum[0] + wsum[1]) + (wsum[2] + wsum[3]);
        atomicAdd(out, blk / (float)NB);
    }
}

extern "C" void kernel_launch(void* const* d_in, const int* in_sizes, int n_in,
                              void* d_out, int out_size, void* d_ws, size_t ws_size,
                              hipStream_t stream) {
    const float* u = (const float*)d_in[0];
    const float* v = (const float*)d_in[1];
    float* out = (float*)d_out;

    char* ws = (char*)d_ws;
    __hip_bfloat16* W = (__hip_bfloat16*)ws;                      // 8 MB
    float* partial = (float*)(ws + (size_t)NW * ND * sizeof(__hip_bfloat16));
    float* pos     = partial + NSTRIP * NB;                       // 8192 floats

    prep_kernel<<<NW / 8, 512, 0, stream>>>(u, v, W, out);
    dcl_main<<<256, 512, 0, stream>>>(W, partial, pos);
    finalize_kernel<<<NB / 256, 256, 0, stream>>>(partial, pos, out);
}

// Round 7
// 155.806 us; speedup vs baseline: 1.8324x; 1.8324x over previous
//
#include <hip/hip_runtime.h>
#include <hip/hip_bf16.h>
#include <stdint.h>

// Problem constants (B=8192, D=256 fixed by reference setup_inputs)
#define NB 8192          // batch rows
#define ND 256           // feature dim (= full K)
#define NW 16384         // rows of W = [v; u]
#define BM 128           // rows per block
#define BN 64            // cols per panel (wave slice = 16 rows)
#define NSH 8            // half-strips
#define SHW 2048         // cols per half-strip
#define NPANEL_B (SHW / BN)    // 32 panels per block
// rows pre-scaled by rw*sqrt(log2e/T): dot == (sim/T)*log2e, so
// exp(sim/T) == exp2(dot) -> single v_exp_f32, no per-element multiply.
#define SQRT_SCALE 4.53981596f  // sqrt(log2(e)/0.07)
#define LN2F 0.69314718f

typedef __bf16 bf16x8 __attribute__((ext_vector_type(8)));
typedef float floatx4 __attribute__((ext_vector_type(4)));

__device__ __forceinline__ void gload_lds16(const void* g, void* l) {
    // async global->LDS, 16B per lane; LDS dest = wave-uniform base + lane*16
    __builtin_amdgcn_global_load_lds(
        (const __attribute__((address_space(1))) unsigned int*)g,
        (__attribute__((address_space(3))) unsigned int*)l,
        16, 0, 0);
}

// ---------------------------------------------------------------------------
// Kernel 1: W[row] = concat(v,u)[row] * (1/||row||) * sqrt(log2e/T), bf16.
// One WAVE per row. Also zeroes out[0] for finalize's atomicAdd.
// ---------------------------------------------------------------------------
__global__ __launch_bounds__(512) void prep_kernel(
    const float* __restrict__ u, const float* __restrict__ v,
    __hip_bfloat16* __restrict__ W, float* __restrict__ out)
{
    const int t    = threadIdx.x;
    if (blockIdx.x == 0 && t == 0) out[0] = 0.f;
    const int row  = blockIdx.x * 8 + (t >> 6);       // 0..16383
    const int lane = t & 63;
    const float* src = (row < NB) ? (v + (size_t)row * ND)
                                  : (u + (size_t)(row - NB) * ND);
    float4 x = ((const float4*)src)[lane];
    float ss = x.x * x.x + x.y * x.y + x.z * x.z + x.w * x.w;
#pragma unroll
    for (int off = 1; off < 64; off <<= 1) ss += __shfl_xor(ss, off, 64);
    const float sc = rsqrtf(ss) * SQRT_SCALE;         // norms ~16, eps clamp moot
    ushort4 o;
    __hip_bfloat16 h;
    h = __float2bfloat16(x.x * sc); o.x = *(const unsigned short*)&h;
    h = __float2bfloat16(x.y * sc); o.y = *(const unsigned short*)&h;
    h = __float2bfloat16(x.z * sc); o.z = *(const unsigned short*)&h;
    h = __float2bfloat16(x.w * sc); o.w = *(const unsigned short*)&h;
    ((ushort4*)(W + (size_t)row * ND))[lane] = o;
}

// ---------------------------------------------------------------------------
// Kernel 2: fused GEMM+exp+rowsum -- r5 structure at 2 blocks/CU.
// Round-6 post-mortem: acc ping-pong spilled (WRITE 156MB scratch); T3/T4
// test corrupted. Round-5 (this structure, ring-4, 128KB LDS) compiled
// clean at VGPR=112 but LDS capped occupancy at 1 block/CU. THIS round's
// single change of substance: halve the ring (2 x 4KB units/wave = 64KB
// LDS) and double the grid (512 blocks) -> 2 blocks/CU, 4 waves/SIMD.
// The measured gap (panel = 2765 cyc vs MFMA 1241 + VALU 940) is idle
// latency no single-block schedule has closed; cross-block TLP is the
// untested lever. Barrier-free: each wave stages its OWN 16 B-rows into
// a private ring-2; counted vmcnt(4) per unit (one unit always in flight).
//  - A fragments global->reg (af[4][8], 32 VGPR), one-time from L2.
//  - exp2 pre-scale: epilogue is bare exp2f (v_exp_f32), no multiply.
//  - pos captured in a register, stored after the loop (vmcnt stays exact).
// Swizzle: 16B chunk c of 256B half-row r at c^r (bijective, 0 conflicts
// in r5). XCD map (r4's): per-XCD 2MB A + 1MB B strip in L2.
// ---------------------------------------------------------------------------
__global__ __launch_bounds__(512, 2) void dcl_main(
    const __hip_bfloat16* __restrict__ W,   // 16384 x 256, pre-scaled
    float* __restrict__ partial,            // [8][8192] slot = half-strip
    float* __restrict__ pos)                // 8192
{
    const int b  = blockIdx.x;
    const int x  = b & 7;                   // XCD (dispatch round-robin)
    const int j  = b >> 3;
    const int sh = ((x & 3) << 1) | (j & 1);          // half-strip 0..7
    const int rt = (j >> 1) | ((x >> 2) << 5);        // row tile 0..63
    const int rb = rt * BM;

    const __hip_bfloat16* A = W + (size_t)NB * ND;    // u rows

    __shared__ __align__(16) char lds[65536];         // 8 waves x ring-2 x 4KB

    const int tid  = threadIdx.x;
    const int wave = tid >> 6;
    const int lane = tid & 63;
    const int wm   = wave >> 2;             // 0..1 : 64-row group of A
    const int wn   = wave & 3;              // 0..3 : 16-col group of panel
    const int quad = lane >> 4;             // 0..3
    const int tcol = lane & 15;             // 0..15
    const int rh4  = lane >> 4;             // stage: row within 4-row group
    const int cc   = lane & 15;             // stage: 16B chunk index (0..15)

    char* const wbuf  = lds + wave * 8192;  // private ring-2
    const int   sbase = sh * SHW;

#define WAITV(N) do {                                                        \
    asm volatile("s_waitcnt vmcnt(" #N ")" ::: "memory");                    \
    __builtin_amdgcn_sched_barrier(0);                                       \
} while (0)

// unit u = (panel u>>1, K-half u&1): 16 rows x 128 k = 4 KB, 4 loads/wave.
#define STAGE(u) do {                                                        \
    const int tu_ = (u) >> 1, h_ = (u) & 1;                                  \
    const int rowb_ = sbase + tu_ * BN + wn * 16;                            \
    char* dst_ = wbuf + ((u) & 1) * 4096;                                    \
    _Pragma("unroll")                                                        \
    for (int i_ = 0; i_ < 4; i_++) {                                         \
        int r_ = i_ * 4 + rh4;                                               \
        gload_lds16(W + (size_t)(rowb_ + r_) * ND + h_ * 128                 \
                      + ((cc ^ r_) << 3),                                    \
                    dst_ + i_ * 1024);                                       \
    }                                                                        \
} while (0)

#define COMPUTE_HALF(u) do {                                                 \
    const char* sb_ = wbuf + ((u) & 1) * 4096;                               \
    const int h_ = (u) & 1;                                                  \
    __builtin_amdgcn_s_setprio(1);                                           \
    _Pragma("unroll")                                                        \
    for (int ks_ = 0; ks_ < 4; ks_++) {                                      \
        bf16x8 bb_ = *(const bf16x8*)(sb_ + tcol * 256 +                     \
                                      ((((ks_ * 4) + quad) ^ tcol) << 4));   \
        _Pragma("unroll")                                                    \
        for (int mt_ = 0; mt_ < 4; mt_++)                                    \
            acc[mt_] = __builtin_amdgcn_mfma_f32_16x16x32_bf16(              \
                af[mt_][h_ * 4 + ks_], bb_, acc[mt_], 0, 0, 0);              \
    }                                                                        \
    __builtin_amdgcn_s_setprio(0);                                           \
} while (0)

#define ACC_INIT() do {                                                      \
    _Pragma("unroll")                                                        \
    for (int mt_ = 0; mt_ < 4; mt_++) acc[mt_] = (floatx4){0.f,0.f,0.f,0.f}; \
} while (0)

// Epilogue for panel p. C/D layout: col=lane&15, row=quad*4+reg (m89/m91).
// acc holds (sim/T)*log2e -> exp2f == exp(sim/T), single v_exp_f32.
#define EPILOGUE(p) do {                                                     \
    const int cb_ = sbase + (p) * BN;                                        \
    if (cb_ != dp) {                                                         \
        _Pragma("unroll")                                                    \
        for (int mt_ = 0; mt_ < 4; mt_++)                                    \
            _Pragma("unroll")                                                \
            for (int rg_ = 0; rg_ < 4; rg_++)                                \
                rsum[mt_][rg_] += exp2f(acc[mt_][rg_]);                      \
    } else {                                                                 \
        _Pragma("unroll")                                                    \
        for (int mt_ = 0; mt_ < 4; mt_++)                                    \
            _Pragma("unroll")                                                \
            for (int rg_ = 0; rg_ < 4; rg_++) {                              \
                int rl_ = mt_ * 16 + quad * 4 + rg_;                         \
                bool sel_ = (rl_ == wn * 16 + tcol);                         \
                float sc_ = acc[mt_][rg_];                                   \
                if (sel_) posv = sc_;                                        \
                rsum[mt_][rg_] += sel_ ? 0.f : exp2f(sc_);                   \
            }                                                                \
    }                                                                        \
} while (0)

    // ---- A fragments: global -> registers (32 VGPRs), issued FIRST so
    // steady-state vmcnt counts see only staging loads ----
    bf16x8 af[4][8];
#pragma unroll
    for (int mt = 0; mt < 4; mt++) {
        const __hip_bfloat16* ar =
            A + (size_t)(rb + wm * 64 + mt * 16 + tcol) * ND + quad * 8;
#pragma unroll
        for (int ks = 0; ks < 8; ks++)
            af[mt][ks] = *(const bf16x8*)(ar + ks * 32);
    }

    // prologue: units 0,1 in flight
    STAGE(0); STAGE(1);

    // diag panel (wave-uniform): dp = global col base of this wave's diag blk
    const bool isuv = (sh < 4);
    int dp = rb + wm * 64 + (isuv ? 0 : NB);
    const bool dvalid = ((dp >> 11) == sh);
    if (!dvalid) dp = 0x40000000;           // sentinel: never matches

    float rsum[4][4];
#pragma unroll
    for (int mt = 0; mt < 4; mt++)
#pragma unroll
        for (int rg = 0; rg < 4; rg++) rsum[mt][rg] = 0.f;

    float posv = 0.f;
    floatx4 acc[4];

    // main loop: panels 0..30 (units 0..61 computed, stages reach unit 63)
#pragma unroll 1
    for (int p = 0; p < NPANEL_B - 1; p++) {
        const int u0 = 2 * p;
        ACC_INIT();
        WAITV(4);                  // unit u0 resident (u0+1 may fly)
        COMPUTE_HALF(u0);
        STAGE(u0 + 2);             // recycle slot0 (u0 consumed)
        WAITV(4);                  // unit u0+1 resident
        COMPUTE_HALF(u0 + 1);
        STAGE(u0 + 3);             // recycle slot1
        __builtin_amdgcn_sched_barrier(0);
        EPILOGUE(p);
    }
    // panel 31: units 62,63 -- drain
    {
        ACC_INIT();
        WAITV(4);  COMPUTE_HALF(62);
        WAITV(0);  COMPUTE_HALF(63);
        __builtin_amdgcn_sched_barrier(0);
        EPILOGUE(31);
    }

#undef WAITV
#undef STAGE
#undef COMPUTE_HALF
#undef ACC_INIT
#undef EPILOGUE

    // diagonal pos store (uv only): holder lane has quad == tcol>>2;
    // convert back to natural units: sim/T = dot * ln2
    if (isuv && dvalid && (tcol >> 2) == quad)
        pos[rb + wm * 64 + wn * 16 + tcol] = posv * LN2F;

    __syncthreads();   // waves are desynced; resync before LDS reuse

    // block-end reduction: quad-lane shuffle, then combine the 4 wn waves in LDS
#pragma unroll
    for (int mt = 0; mt < 4; mt++)
#pragma unroll
        for (int reg = 0; reg < 4; reg++) {
            float vsum = rsum[mt][reg];
            vsum += __shfl_xor(vsum, 1, 64);
            vsum += __shfl_xor(vsum, 2, 64);
            vsum += __shfl_xor(vsum, 4, 64);
            vsum += __shfl_xor(vsum, 8, 64);
            if (tcol == 0) {
                int lrow = wm * 64 + mt * 16 + quad * 4 + reg;
                ((float*)lds)[wn * 128 + lrow] = vsum;
            }
        }
    __syncthreads();
    if (tid < BM) {
        const float* lf = (const float*)lds;
        float t = lf[tid] + lf[128 + tid] + lf[256 + tid] + lf[384 + tid];
        partial[(size_t)sh * NB + rb + tid] = t;
    }
}

// ---------------------------------------------------------------------------
// Kernel 3: loss = mean_i( log(sum_half_strips partial[s][i]) - pos_i )
// 32 blocks x 256 thr, device atomicAdd into out[0] (zeroed by prep).
// ---------------------------------------------------------------------------
__global__ __launch_bounds__(256) void finalize_kernel(
    const float* __restrict__ partial, const float* __restrict__ pos,
    float* __restrict__ out)
{
    const int i = blockIdx.x * 256 + threadIdx.x;   // 0..8191
    float tot = 0.f;
#pragma unroll
    for (int k = 0; k < NSH; k++) tot += partial[(size_t)k * NB + i];
    float sv = logf(tot) - pos[i];
#pragma unroll
    for (int off = 32; off > 0; off >>= 1) sv += __shfl_down(sv, off, 64);
    __shared__ float wsum[4];
    const int t = threadIdx.x;
    if ((t & 63) == 0) wsum[t >> 6] = sv;
    __syncthreads();
    if (t == 0) {
        float blk = (wsum[0] + wsum[1]) + (wsum[2] + wsum[3]);
        atomicAdd(out, blk / (float)NB);
    }
}

extern "C" void kernel_launch(void* const* d_in, const int* in_sizes, int n_in,
                              void* d_out, int out_size, void* d_ws, size_t ws_size,
                              hipStream_t stream) {
    const float* u = (const float*)d_in[0];
    const float* v = (const float*)d_in[1];
    float* out = (float*)d_out;

    char* ws = (char*)d_ws;
    __hip_bfloat16* W = (__hip_bfloat16*)ws;                      // 8 MB
    float* partial = (float*)(ws + (size_t)NW * ND * sizeof(__hip_bfloat16));
    float* pos     = partial + NSH * NB;                          // 8192 floats

    prep_kernel<<<NW / 8, 512, 0, stream>>>(u, v, W, out);
    dcl_main<<<512, 512, 0, stream>>>(W, partial, pos);
    finalize_kernel<<<NB / 256, 256, 0, stream>>>(partial, pos, out);
}

// Round 8
// 135.587 us; speedup vs baseline: 2.1056x; 1.1491x over previous
//
#include <hip/hip_runtime.h>
#include <hip/hip_bf16.h>
#include <stdint.h>

// Problem constants (B=8192, D=256 fixed by reference setup_inputs)
#define NB 8192          // batch rows
#define ND 256           // feature dim (= full K)
#define NW 16384         // rows of W = [v; u]
#define BM 128           // rows per block
#define BN 64            // cols per panel
#define NSTRIP 4         // column strips
#define STRIPW 4096      // cols per strip
#define NPANEL (STRIPW / BN)   // 64 panels per block
// rows pre-scaled by rw*sqrt(log2e/T): dot == (sim/T)*log2e, so
// exp(sim/T) == exp2(dot) -> one raw v_exp_f32, no multiply, no guards.
#define SQRT_SCALE 4.53981596f  // sqrt(log2(e)/0.07)
#define LN2F 0.69314718f

typedef __bf16 bf16x8 __attribute__((ext_vector_type(8)));
typedef float floatx4 __attribute__((ext_vector_type(4)));

__device__ __forceinline__ void gload_lds16(const void* g, void* l) {
    // async global->LDS, 16B per lane; LDS dest = wave-uniform base + lane*16
    __builtin_amdgcn_global_load_lds(
        (const __attribute__((address_space(1))) unsigned int*)g,
        (__attribute__((address_space(3))) unsigned int*)l,
        16, 0, 0);
}

// raw v_exp_f32 (r7 lesson: exp2f() is an OCML call with denorm guards,
// ~14 cyc vs 4; inputs here are bounded |x|<~25 so the raw op is exact)
__device__ __forceinline__ float fexp2(float x) {
    return __builtin_amdgcn_exp2f(x);
}

// ---------------------------------------------------------------------------
// Kernel 1: W[row] = concat(v,u)[row] * (1/||row||) * sqrt(log2e/T), bf16.
// One WAVE per row. Also zeroes out[0] for finalize's atomicAdd.
// ---------------------------------------------------------------------------
__global__ __launch_bounds__(512) void prep_kernel(
    const float* __restrict__ u, const float* __restrict__ v,
    __hip_bfloat16* __restrict__ W, float* __restrict__ out)
{
    const int t    = threadIdx.x;
    if (blockIdx.x == 0 && t == 0) out[0] = 0.f;
    const int row  = blockIdx.x * 8 + (t >> 6);       // 0..16383
    const int lane = t & 63;
    const float* src = (row < NB) ? (v + (size_t)row * ND)
                                  : (u + (size_t)(row - NB) * ND);
    float4 x = ((const float4*)src)[lane];
    float ss = x.x * x.x + x.y * x.y + x.z * x.z + x.w * x.w;
#pragma unroll
    for (int off = 1; off < 64; off <<= 1) ss += __shfl_xor(ss, off, 64);
    const float sc = rsqrtf(ss) * SQRT_SCALE;         // norms ~16, eps clamp moot
    ushort4 o;
    __hip_bfloat16 h;
    h = __float2bfloat16(x.x * sc); o.x = *(const unsigned short*)&h;
    h = __float2bfloat16(x.y * sc); o.y = *(const unsigned short*)&h;
    h = __float2bfloat16(x.z * sc); o.z = *(const unsigned short*)&h;
    h = __float2bfloat16(x.w * sc); o.w = *(const unsigned short*)&h;
    ((ushort4*)(W + (size_t)row * ND))[lane] = o;
}

// ---------------------------------------------------------------------------
// Kernel 2: fused GEMM+exp+rowsum -- T3+T4 clean port (block-shared ring-4).
// Round-7 post-mortem: ring-2 slack too small (Mfma 29%); occupancy >1
// block/CU is unreachable at this register footprint (r3/r4/r7) -- so
// extract overlap at 2 waves/SIMD:
//  - B panels (64 cols x 256 K = 32 KB) staged BLOCK-SHARED into a ring-4
//    (128 KB LDS). Halves L2 traffic vs r2's private staging (2 MB/CU) and
//    halves staging VALU (4 gloads/wave/panel).
//  - Per panel: s_waitcnt vmcnt(8) [my 4 loads for panel t done; t+1,t+2
//    stay in flight = 2 panels ~1200 cyc slack > worst L2 latency ~900]
//    -> RAW s_barrier (no compiler vmcnt(0) drain; all waves' loads for t
//    done because each waited before the same barrier) -> STAGE(t+3) into
//    slot (t-1)%4 (reads of it finished last panel, ordered by this
//    barrier) -> setprio(1) -> 32 MFMA + 16 exp2 UNFENCED in one region
//    (exps fill MFMA shadows) -> setprio(0).
//  - Single acc (no ping-pong: r6's spill trigger). pos captured in a
//    register, stored after the loop -> no vmem ops pollute vmcnt counts.
//  - A fragments global->reg (af[4][8], 32 VGPR), one-time from L2.
// Swizzle (verified r1..r7, 0 conflicts): 16B chunk c of row r at c^(r&15);
// linear LDS dest + inverse-swizzled global source + swizzle on read.
// XCD map: s=(b>>1)&3, rt=((b>>3)<<1)|(b&1); per-XCD working set ~4MB L2.
// ---------------------------------------------------------------------------
__global__ __launch_bounds__(512, 2) void dcl_main(
    const __hip_bfloat16* __restrict__ W,   // 16384 x 256, pre-scaled
    float* __restrict__ partial,            // [4][8192] slot = strip
    float* __restrict__ pos)                // 8192
{
    const int b  = blockIdx.x;
    const int s  = (b >> 1) & 3;                    // strip; XCD(b)=b%8 in {2s,2s+1}
    const int rt = ((b >> 3) << 1) | (b & 1);       // row tile 0..63
    const int rb = rt * BM;

    const __hip_bfloat16* A = W + (size_t)NB * ND;  // u rows

    __shared__ __align__(16) char lds[131072];      // ring-4 x 32 KB panels

    const int tid  = threadIdx.x;
    const int wave = tid >> 6;
    const int lane = tid & 63;
    const int wm   = wave >> 2;             // 0..1 : 64-row group of A
    const int wn   = wave & 3;              // 0..3 : 16-col group of panel
    const int quad = lane >> 4;             // 0..3
    const int tcol = lane & 15;             // 0..15
    const int rh   = lane >> 5;             // stage: row half within 1KB chunk
    const int cl   = lane & 31;             // stage: 16B chunk index (0..31)

    const int sbase = s * STRIPW;

#define WAITV(N) do {                                                        \
    asm volatile("s_waitcnt vmcnt(" #N ")" ::: "memory");                    \
    __builtin_amdgcn_sched_barrier(0);                                       \
} while (0)

// Stage panel T (32 KB) block-shared: wave stages local rows [wave*8,+8),
// 4 x 1KB gloads (each covers 2 rows: lanes 0-31 row r, 32-63 row r+1).
#define STAGE(T) do {                                                        \
    char* dst_ = lds + ((T) & 3) * 32768 + wave * 4096;                      \
    const int cb_ = sbase + (T) * BN;                                        \
    _Pragma("unroll")                                                        \
    for (int i_ = 0; i_ < 4; i_++) {                                         \
        int rl_ = wave * 8 + i_ * 2 + rh;        /* local row 0..63 */       \
        gload_lds16(W + (size_t)(cb_ + rl_) * ND + ((cl ^ (rl_ & 15)) << 3), \
                    dst_ + i_ * 1024);                                       \
    }                                                                        \
} while (0)

#define COMPUTE(T) do {                                                      \
    const char* sb_ = lds + ((T) & 3) * 32768;                               \
    _Pragma("unroll")                                                        \
    for (int mt_ = 0; mt_ < 4; mt_++) acc[mt_] = (floatx4){0.f,0.f,0.f,0.f}; \
    _Pragma("unroll")                                                        \
    for (int ks_ = 0; ks_ < 8; ks_++) {                                      \
        bf16x8 bb_ = *(const bf16x8*)(sb_ + (wn * 16 + tcol) * 512 +         \
                                      ((((ks_ * 4) + quad) ^ tcol) << 4));   \
        _Pragma("unroll")                                                    \
        for (int mt_ = 0; mt_ < 4; mt_++)                                    \
            acc[mt_] = __builtin_amdgcn_mfma_f32_16x16x32_bf16(              \
                af[mt_][ks_], bb_, acc[mt_], 0, 0, 0);                       \
    }                                                                        \
} while (0)

// Epilogue for panel T (unfenced after COMPUTE: exps co-schedule with the
// MFMA tail). C/D layout: col=lane&15, row=quad*4+reg (m89/m91).
#define EPILOGUE(T) do {                                                     \
    const int cbE_ = sbase + (T) * BN;                                       \
    if (cbE_ != dp) {                                                        \
        _Pragma("unroll")                                                    \
        for (int mt_ = 0; mt_ < 4; mt_++)                                    \
            _Pragma("unroll")                                                \
            for (int rg_ = 0; rg_ < 4; rg_++)                                \
                rsum[mt_][rg_] += fexp2(acc[mt_][rg_]);                      \
    } else {                                                                 \
        _Pragma("unroll")                                                    \
        for (int mt_ = 0; mt_ < 4; mt_++)                                    \
            _Pragma("unroll")                                                \
            for (int rg_ = 0; rg_ < 4; rg_++) {                              \
                int rl_ = mt_ * 16 + quad * 4 + rg_;                         \
                bool sel_ = (rl_ == wn * 16 + tcol);                         \
                float sc_ = acc[mt_][rg_];                                   \
                if (sel_) posv = sc_;                                        \
                rsum[mt_][rg_] += sel_ ? 0.f : fexp2(sc_);                   \
            }                                                                \
    }                                                                        \
} while (0)

#define PANEL_BODY(T) do {                                                   \
    __builtin_amdgcn_s_setprio(1);                                           \
    COMPUTE(T);                                                              \
    EPILOGUE(T);                                                             \
    __builtin_amdgcn_s_setprio(0);                                           \
} while (0)

    // ---- A fragments: global -> registers (32 VGPRs), issued FIRST so
    // they are the oldest vmem ops and drain under the prologue waits ----
    bf16x8 af[4][8];
#pragma unroll
    for (int mt = 0; mt < 4; mt++) {
        const __hip_bfloat16* ar =
            A + (size_t)(rb + wm * 64 + mt * 16 + tcol) * ND + quad * 8;
#pragma unroll
        for (int ks = 0; ks < 8; ks++)
            af[mt][ks] = *(const bf16x8*)(ar + ks * 32);
    }

    // prologue: panels 0..2 in flight (12 loads/wave)
    STAGE(0); STAGE(1); STAGE(2);

    // diag panel (wave-uniform): dp = global col base of this wave's diag blk
    const bool isuv = (s < 2);
    int dp = rb + wm * 64 + (isuv ? 0 : NB);
    const bool dvalid = ((dp >> 12) == s);
    if (!dvalid) dp = 0x40000000;           // sentinel: never matches

    float rsum[4][4];
#pragma unroll
    for (int mt = 0; mt < 4; mt++)
#pragma unroll
        for (int rg = 0; rg < 4; rg++) rsum[mt][rg] = 0.f;

    float posv = 0.f;
    floatx4 acc[4];

    // main loop: panels 0..60 stage t+3; 61..63 drain the pipeline
#pragma unroll 1
    for (int t = 0; t < NPANEL - 3; t++) {
        WAITV(8);                          // panel t resident (t+1,t+2 fly)
        __builtin_amdgcn_s_barrier();      // all waves' loads for t done
        STAGE(t + 3);                      // slot (t-1)%4: reads done last panel
        __builtin_amdgcn_sched_barrier(0); // pin load issue before compute
        PANEL_BODY(t);
    }
    WAITV(8);  __builtin_amdgcn_s_barrier(); PANEL_BODY(61);
    WAITV(4);  __builtin_amdgcn_s_barrier(); PANEL_BODY(62);
    WAITV(0);  __builtin_amdgcn_s_barrier(); PANEL_BODY(63);

#undef WAITV
#undef STAGE
#undef COMPUTE
#undef EPILOGUE
#undef PANEL_BODY

    // diagonal pos store (uv only): holder lane has quad == tcol>>2;
    // convert log2-units back: sim/T = dot * ln2
    if (isuv && dvalid && (tcol >> 2) == quad)
        pos[rb + wm * 64 + wn * 16 + tcol] = posv * LN2F;

    __syncthreads();   // all panel reads done before LDS reuse

    // block-end reduction: quad-lane shuffle, then combine the 4 wn waves in LDS
#pragma unroll
    for (int mt = 0; mt < 4; mt++)
#pragma unroll
        for (int reg = 0; reg < 4; reg++) {
            float vsum = rsum[mt][reg];
            vsum += __shfl_xor(vsum, 1, 64);
            vsum += __shfl_xor(vsum, 2, 64);
            vsum += __shfl_xor(vsum, 4, 64);
            vsum += __shfl_xor(vsum, 8, 64);
            if (tcol == 0) {
                int lrow = wm * 64 + mt * 16 + quad * 4 + reg;
                ((float*)lds)[wn * 128 + lrow] = vsum;
            }
        }
    __syncthreads();
    if (tid < BM) {
        const float* lf = (const float*)lds;
        float t = lf[tid] + lf[128 + tid] + lf[256 + tid] + lf[384 + tid];
        partial[(size_t)s * NB + rb + tid] = t;
    }
}

// ---------------------------------------------------------------------------
// Kernel 3: loss = mean_i( log(sum_strips partial[s][i]) - pos_i )
// 32 blocks x 256 thr, device atomicAdd into out[0] (zeroed by prep).
// ---------------------------------------------------------------------------
__global__ __launch_bounds__(256) void finalize_kernel(
    const float* __restrict__ partial, const float* __restrict__ pos,
    float* __restrict__ out)
{
    const int i = blockIdx.x * 256 + threadIdx.x;   // 0..8191
    float tot = partial[i] + partial[NB + i] + partial[2 * NB + i]
              + partial[3 * NB + i];
    float sv = logf(tot) - pos[i];
#pragma unroll
    for (int off = 32; off > 0; off >>= 1) sv += __shfl_down(sv, off, 64);
    __shared__ float wsum[4];
    const int t = threadIdx.x;
    if ((t & 63) == 0) wsum[t >> 6] = sv;
    __syncthreads();
    if (t == 0) {
        float blk = (wsum[0] + wsum[1]) + (wsum[2] + wsum[3]);
        atomicAdd(out, blk / (float)NB);
    }
}

extern "C" void kernel_launch(void* const* d_in, const int* in_sizes, int n_in,
                              void* d_out, int out_size, void* d_ws, size_t ws_size,
                              hipStream_t stream) {
    const float* u = (const float*)d_in[0];
    const float* v = (const float*)d_in[1];
    float* out = (float*)d_out;

    char* ws = (char*)d_ws;
    __hip_bfloat16* W = (__hip_bfloat16*)ws;                      // 8 MB
    float* partial = (float*)(ws + (size_t)NW * ND * sizeof(__hip_bfloat16));
    float* pos     = partial + NSTRIP * NB;                       // 8192 floats

    prep_kernel<<<NW / 8, 512, 0, stream>>>(u, v, W, out);
    dcl_main<<<256, 512, 0, stream>>>(W, partial, pos);
    finalize_kernel<<<NB / 256, 256, 0, stream>>>(partial, pos, out);
}